// Round 1
// baseline (266.507 us; speedup 1.0000x reference)
//
#include <hip/hip_runtime.h>
#include <hip/hip_bf16.h>

// QuantizedLinear: q = clip(round(lin/s)), s = max|lin|/127,
// lin = (x_q - x_zp) @ w_q^T + round(fp_bias / (w_scale*x_scale))
// Exact-integer path: x8 = x_q-128 (int8), w8 = w_q (int8),
// lin = x8@w8^T + (128 - x_zp[b])*rowsum(w) + qbias   (all int32, exact)

typedef int i32x4 __attribute__((ext_vector_type(4)));

#define AS1 __attribute__((address_space(1)))
#define AS3 __attribute__((address_space(3)))

__device__ __forceinline__ void async16(const void* g, void* lds) {
    __builtin_amdgcn_global_load_lds((const AS1 void*)g, (AS3 void*)lds, 16, 0, 0);
}

// ---- pass 1a: x8[i] = (int8)(x_q[i] - 128); also zero the global max ----
__global__ void conv_x_kernel(const float4* __restrict__ xq, int* __restrict__ x8,
                              int* gmax, int n4) {
    int i = blockIdx.x * 256 + threadIdx.x;
    if (i == 0) *gmax = 0;
    if (i >= n4) return;
    float4 v = xq[i];
    int b0 = ((int)v.x - 128) & 255;
    int b1 = ((int)v.y - 128) & 255;
    int b2 = ((int)v.z - 128) & 255;
    int b3 = ((int)v.w - 128) & 255;
    x8[i] = b0 | (b1 << 8) | (b2 << 16) | (b3 << 24);
}

// ---- pass 1b: w8 = (int8)w_q; rowsum[n] = sum_k w_q[n][k] ----
__global__ void conv_w_kernel(const float* __restrict__ wq, int* __restrict__ w8,
                              int* __restrict__ rowsum, int K) {
    int row = blockIdx.x;
    int t = threadIdx.x;
    const float4* src = (const float4*)(wq + (size_t)row * K);
    int* dst = w8 + (size_t)row * (K >> 2);
    int sum = 0;
    int passes = K >> 10;  // 256 threads * 4 elements
    for (int p = 0; p < passes; ++p) {
        float4 v = src[p * 256 + t];
        int b0 = (int)v.x, b1 = (int)v.y, b2 = (int)v.z, b3 = (int)v.w;
        sum += b0 + b1 + b2 + b3;
        dst[p * 256 + t] = (b0 & 255) | ((b1 & 255) << 8) | ((b2 & 255) << 16) | ((b3 & 255) << 24);
    }
    #pragma unroll
    for (int m = 32; m; m >>= 1) sum += __shfl_xor(sum, m, 64);
    __shared__ int wsum[4];
    if ((t & 63) == 0) wsum[t >> 6] = sum;
    __syncthreads();
    if (t == 0) rowsum[row] = wsum[0] + wsum[1] + wsum[2] + wsum[3];
}

// ---- pass 2: int8 GEMM, 128x128 tile, BK=64, m97 structure ----
// lin (int32) written into the q region of d_out; block max -> atomicMax(gmax)
__global__ __launch_bounds__(256, 3) void gemm_i8_kernel(
    const char* __restrict__ x8, const char* __restrict__ w8,
    const int* __restrict__ w_rowsum,
    const float* __restrict__ x_scale, const float* __restrict__ x_zp,
    const float* __restrict__ fp_bias, const float* __restrict__ w_scale_p,
    int* __restrict__ lin_out, int* gmax, int N, int K) {
    __shared__ char ldsA[128 * 64];
    __shared__ char ldsB[128 * 64];
    __shared__ int s_bmax;

    const int t = threadIdx.x;
    const int w = t >> 6, l = t & 63;
    const int tm = blockIdx.y, tn = blockIdx.x;
    if (t == 0) s_bmax = 0;

    // staging: chunk c = t (rows 0..63) and c = t+256 (rows 64..127)
    // LDS is linear [row][slot], source k-group is XOR-swizzled so that the
    // read-side swizzle spreads ds_read_b128 across all 8 bank groups.
    const int srow = t >> 2;
    const int slot = t & 3;
    const int kg = slot ^ ((srow >> 1) & 3);  // same for srow and srow+64
    const char* gA = x8 + ((size_t)(tm * 128 + srow)) * K + kg * 16;
    const char* gB = w8 + ((size_t)(tn * 128 + srow)) * K + kg * 16;
    char* dstA0 = ldsA + w * 1024;
    char* dstA1 = ldsA + 4096 + w * 1024;
    char* dstB0 = ldsB + w * 1024;
    char* dstB1 = ldsB + 4096 + w * 1024;

    // fragment read offsets (swizzled)
    const int lane_lo = l & 15, lane_hi = l >> 4;
    const int wm = w >> 1, wn = w & 1;
    const int ar = wm * 64 + lane_lo;
    const int aoff = ar * 64 + (lane_hi ^ ((ar >> 1) & 3)) * 16;
    const int br = wn * 64 + lane_lo;
    const int boff = br * 64 + (lane_hi ^ ((br >> 1) & 3)) * 16;

    i32x4 acc[4][4] = {};

    const int KITERS = K >> 6;
    for (int kt = 0; kt < KITERS; ++kt) {
        const char* pa = gA + (size_t)kt * 64;
        const char* pb = gB + (size_t)kt * 64;
        async16(pa, dstA0);
        async16(pa + (size_t)64 * K, dstA1);
        async16(pb, dstB0);
        async16(pb + (size_t)64 * K, dstB1);
        __syncthreads();
        i32x4 af[4], bf[4];
        #pragma unroll
        for (int m = 0; m < 4; ++m) af[m] = *(const i32x4*)(ldsA + aoff + m * 1024);
        #pragma unroll
        for (int n = 0; n < 4; ++n) bf[n] = *(const i32x4*)(ldsB + boff + n * 1024);
        #pragma unroll
        for (int m = 0; m < 4; ++m)
            #pragma unroll
            for (int n = 0; n < 4; ++n)
                acc[m][n] = __builtin_amdgcn_mfma_i32_16x16x64_i8(af[m], bf[n], acc[m][n], 0, 0, 0);
        __syncthreads();
    }

    // epilogue: lin = acc + z*rowsum + round(fp_bias/(ws*xs)); track max|lin|
    const float ws = *w_scale_p;
    const int rowg0 = tm * 128 + wm * 64 + lane_hi * 4;  // + m*16 + j
    const int colg0 = tn * 128 + wn * 64 + lane_lo;      // + n*16
    float xs[16];
    int zz[16];
    #pragma unroll
    for (int m = 0; m < 4; ++m)
        #pragma unroll
        for (int j = 0; j < 4; ++j) {
            int r = rowg0 + m * 16 + j;
            xs[m * 4 + j] = x_scale[r];
            zz[m * 4 + j] = 128 - (int)x_zp[r];
        }
    int lmax = 0;
    #pragma unroll
    for (int n = 0; n < 4; ++n) {
        int col = colg0 + n * 16;
        float fb = fp_bias[col];
        int wrs = w_rowsum[col];
        #pragma unroll
        for (int m = 0; m < 4; ++m)
            #pragma unroll
            for (int j = 0; j < 4; ++j) {
                int idx = m * 4 + j;
                int qb = (int)rintf(fb / (ws * xs[idx]));
                int lin = acc[m][n][j] + zz[idx] * wrs + qb;
                int a = lin < 0 ? -lin : lin;
                lmax = a > lmax ? a : lmax;
                lin_out[(size_t)(rowg0 + m * 16 + j) * N + col] = lin;
            }
    }
    atomicMax(&s_bmax, lmax);
    __syncthreads();
    if (t == 0) atomicMax(gmax, s_bmax);
}

// ---- pass 3: requantize in place (int32 lin -> float q) ----
__global__ void requant_kernel(float4* qout, const int4* lin, const int* gmax, int n4) {
    int i = blockIdx.x * 256 + threadIdx.x;
    if (i >= n4) return;
    float s = (float)(*gmax) / 127.0f;
    int4 v = lin[i];
    float4 o;
    o.x = fminf(127.0f, fmaxf(-127.0f, rintf((float)v.x / s)));
    o.y = fminf(127.0f, fmaxf(-127.0f, rintf((float)v.y / s)));
    o.z = fminf(127.0f, fmaxf(-127.0f, rintf((float)v.z / s)));
    o.w = fminf(127.0f, fmaxf(-127.0f, rintf((float)v.w / s)));
    qout[i] = o;
}

// ---- pass 4: out_scale[b] = s * x_scale[b] * w_scale; zero_point = 0 ----
__global__ void scale_kernel(float* __restrict__ out_scale, float* __restrict__ out_zp,
                             const float* __restrict__ x_scale,
                             const float* __restrict__ w_scale_p,
                             const int* gmax, int B) {
    int i = blockIdx.x * 256 + threadIdx.x;
    if (i >= B) return;
    float s = (float)(*gmax) / 127.0f;
    out_scale[i] = s * x_scale[i] * w_scale_p[0];
    out_zp[i] = 0.0f;
}

extern "C" void kernel_launch(void* const* d_in, const int* in_sizes, int n_in,
                              void* d_out, int out_size, void* d_ws, size_t ws_size,
                              hipStream_t stream) {
    const float* x_q     = (const float*)d_in[0];
    const float* x_scale = (const float*)d_in[1];
    const float* x_zp    = (const float*)d_in[2];
    const float* w_q     = (const float*)d_in[3];
    const float* w_scale = (const float*)d_in[4];
    const float* fp_bias = (const float*)d_in[5];

    const int B   = in_sizes[1];           // 8192
    const int IN  = in_sizes[0] / B;       // 4096
    const int OUT = in_sizes[5];           // 4096

    float* q         = (float*)d_out;
    float* out_scale = q + (size_t)B * OUT;
    float* out_zp    = out_scale + B;

    // workspace layout
    char* ws    = (char*)d_ws;
    int* gmax   = (int*)ws;
    char* x8    = ws + 64;
    char* w8    = x8 + (size_t)B * IN;
    int* rowsum = (int*)(w8 + (size_t)OUT * IN);
    size_t needed = 64 + (size_t)B * IN + (size_t)OUT * IN + (size_t)OUT * 4;
    if (ws_size < needed) return;  // would corrupt; fail loudly with zero output

    int n4x = (B * IN) >> 2;
    conv_x_kernel<<<(n4x + 255) / 256, 256, 0, stream>>>((const float4*)x_q, (int*)x8, gmax, n4x);
    conv_w_kernel<<<OUT, 256, 0, stream>>>(w_q, (int*)w8, rowsum, IN);

    dim3 grid(OUT / 128, B / 128);
    gemm_i8_kernel<<<grid, 256, 0, stream>>>(x8, w8, rowsum, x_scale, x_zp, fp_bias,
                                             w_scale, (int*)q, gmax, OUT, IN);

    int n4q = (B * OUT) >> 2;
    requant_kernel<<<(n4q + 255) / 256, 256, 0, stream>>>((float4*)q, (const int4*)q, gmax, n4q);
    scale_kernel<<<(B + 255) / 256, 256, 0, stream>>>(out_scale, out_zp, x_scale, w_scale, gmax, B);
}